// Round 1
// baseline (33.238 us; speedup 1.0000x reference)
//
#include <hip/hip_runtime.h>
#include <math.h>

// SentAttNet: scores = tanh(x[b,s,:]·w + bias); attn = masked softmax over S.
// B=4096 rows, S=2048, F=4 (one float4 per (b,s)). One block per row.

#define S_LEN 2048
#define BLOCK 256
#define PER_THREAD (S_LEN / BLOCK)  // 8

__global__ __launch_bounds__(BLOCK) void sent_att_kernel(
    const float* __restrict__ x,     // [B, S, 4]
    const float* __restrict__ w,     // [4, 1]
    const float* __restrict__ bias,  // [1]
    float* __restrict__ out)         // [B, S]
{
    const int b = blockIdx.x;
    const int t = threadIdx.x;
    const float4* __restrict__ xrow =
        reinterpret_cast<const float4*>(x) + (size_t)b * S_LEN;

    const float w0 = w[0], w1 = w[1], w2 = w[2], w3 = w[3];
    const float cb = bias[0];

    // Pass 1 (registers): scores + local max
    float sc[PER_THREAD];
    float lmax = -INFINITY;
#pragma unroll
    for (int k = 0; k < PER_THREAD; ++k) {
        const int s = t + k * BLOCK;          // coalesced float4 loads
        const float4 v = xrow[s];
        const float z = v.x * w0 + v.y * w1 + v.z * w2 + v.w * w3 + cb;
        const float sv = tanhf(z);
        sc[k] = sv;
        lmax = fmaxf(lmax, sv);
    }

    // Block-reduce max (wave64 shuffle + 4-entry LDS)
#pragma unroll
    for (int off = 32; off > 0; off >>= 1)
        lmax = fmaxf(lmax, __shfl_xor(lmax, off, 64));

    __shared__ float smax[BLOCK / 64];
    __shared__ float ssum[BLOCK / 64];
    const int wave = t >> 6;
    const int lane = t & 63;
    if (lane == 0) smax[wave] = lmax;
    __syncthreads();
    const float m = fmaxf(fmaxf(smax[0], smax[1]), fmaxf(smax[2], smax[3]));

    // Pass 2 (registers): e = exp(sc - m) * (sc != 0), local sum
    float e[PER_THREAD];
    float lsum = 0.0f;
#pragma unroll
    for (int k = 0; k < PER_THREAD; ++k) {
        const float sv = sc[k];
        const float ev = (sv != 0.0f) ? expf(sv - m) : 0.0f;
        e[k] = ev;
        lsum += ev;
    }

#pragma unroll
    for (int off = 32; off > 0; off >>= 1)
        lsum += __shfl_xor(lsum, off, 64);
    if (lane == 0) ssum[wave] = lsum;
    __syncthreads();
    const float total = ssum[0] + ssum[1] + ssum[2] + ssum[3];
    const float inv = 1.0f / total;

    // Write normalized attention (coalesced)
    float* __restrict__ orow = out + (size_t)b * S_LEN;
#pragma unroll
    for (int k = 0; k < PER_THREAD; ++k)
        orow[t + k * BLOCK] = e[k] * inv;
}

extern "C" void kernel_launch(void* const* d_in, const int* in_sizes, int n_in,
                              void* d_out, int out_size, void* d_ws, size_t ws_size,
                              hipStream_t stream) {
    const float* x    = (const float*)d_in[0];  // [B, S, F]
    const float* w    = (const float*)d_in[1];  // [F, 1]
    const float* bias = (const float*)d_in[2];  // [1]
    float* out = (float*)d_out;                 // [B, S]

    const int B = in_sizes[0] / (S_LEN * 4);    // 4096
    sent_att_kernel<<<B, BLOCK, 0, stream>>>(x, w, bias, out);
}

// Round 2
// 29.269 us; speedup vs baseline: 1.1356x; 1.1356x over previous
//
#include <hip/hip_runtime.h>
#include <math.h>

// SentAttNet: scores = tanh(x[b,s,:]·w + bias); attn = masked softmax over S.
// B=4096 rows, S=2048, F=4 (one float4 per (b,s)). One block per row.
// Memory-bound: 134 MB in + 33.5 MB out. Strategy: single pass over x,
// scores->exp kept in registers, ONE block reduction (sum only — tanh is
// bounded so no max-shift needed; reference's shift is math-equivalent).

#define S_LEN 2048
#define BLOCK 256
#define PER_THREAD (S_LEN / BLOCK)  // 8

__device__ __forceinline__ float fast_tanh(float z) {
    // tanh(z) = (e^{2z} - 1) / (e^{2z} + 1); clamp so e^{2z} can't overflow.
    z = fminf(fmaxf(z, -20.0f), 20.0f);
    const float t2 = __expf(2.0f * z);           // v_mul + v_exp_f32
    return (t2 - 1.0f) * __builtin_amdgcn_rcpf(t2 + 1.0f);  // ~1 ulp
}

__global__ __launch_bounds__(BLOCK) void sent_att_kernel(
    const float* __restrict__ x,     // [B, S, 4]
    const float* __restrict__ w,     // [4, 1]
    const float* __restrict__ bias,  // [1]
    float* __restrict__ out)         // [B, S]
{
    const int b = blockIdx.x;
    const int t = threadIdx.x;
    const float4* __restrict__ xrow =
        reinterpret_cast<const float4*>(x) + (size_t)b * S_LEN;

    const float w0 = w[0], w1 = w[1], w2 = w[2], w3 = w[3];
    const float cb = bias[0];

    // Single pass: load, score, exp, mask — all in registers.
    float e[PER_THREAD];
    float lsum = 0.0f;
#pragma unroll
    for (int k = 0; k < PER_THREAD; ++k) {
        const int s = t + k * BLOCK;             // coalesced float4 loads
        const float4 v = xrow[s];
        const float z = v.x * w0 + v.y * w1 + v.z * w2 + v.w * w3 + cb;
        const float sv = fast_tanh(z);
        // exp(sv) is bounded in [e^-1, e^1]: no shift needed.
        const float ev = (sv != 0.0f) ? __expf(sv) : 0.0f;
        e[k] = ev;
        lsum += ev;
    }

    // Block-reduce sum (wave64 butterfly + 4-entry LDS)
#pragma unroll
    for (int off = 32; off > 0; off >>= 1)
        lsum += __shfl_xor(lsum, off, 64);

    __shared__ float ssum[BLOCK / 64];
    const int wave = t >> 6;
    const int lane = t & 63;
    if (lane == 0) ssum[wave] = lsum;
    __syncthreads();
    const float total = ssum[0] + ssum[1] + ssum[2] + ssum[3];
    const float inv = 1.0f / total;

    // Write normalized attention (coalesced)
    float* __restrict__ orow = out + (size_t)b * S_LEN;
#pragma unroll
    for (int k = 0; k < PER_THREAD; ++k)
        orow[t + k * BLOCK] = e[k] * inv;
}

extern "C" void kernel_launch(void* const* d_in, const int* in_sizes, int n_in,
                              void* d_out, int out_size, void* d_ws, size_t ws_size,
                              hipStream_t stream) {
    const float* x    = (const float*)d_in[0];  // [B, S, F]
    const float* w    = (const float*)d_in[1];  // [F, 1]
    const float* bias = (const float*)d_in[2];  // [1]
    float* out = (float*)d_out;                 // [B, S]

    const int B = in_sizes[0] / (S_LEN * 4);    // 4096
    sent_att_kernel<<<B, BLOCK, 0, stream>>>(x, w, bias, out);
}